// Round 5
// baseline (1027.937 us; speedup 1.0000x reference)
//
#include <hip/hip_runtime.h>
#include <math.h>

#define NB 4096
#define NR 49
#define NS 50
#define ND 512
#define NK 100
#define NT 7            // N-tiles of 16 cols (112 >= 100)
#define KSTEPS 16       // 512 / 32 (global k-steps)
#define CHUNK_KS 8      // k-steps per LDS chunk (256 cols)
#define FRAGS (NT * KSTEPS * 64 * 8)   // 57344 ushorts (114688 B) per weight matrix

typedef __attribute__((ext_vector_type(8))) short short8;
typedef __attribute__((ext_vector_type(4))) float f32x4;

__device__ __forceinline__ unsigned short f32_bf16(float f) {
    union { float f; unsigned u; } x; x.f = f;
    return (unsigned short)((x.u + 0x7fffu + ((x.u >> 16) & 1u)) >> 16);  // RNE
}
__device__ __forceinline__ unsigned cvt_pk_bf16(float lo, float hi) {
    unsigned r;
    asm("v_cvt_pk_bf16_f32 %0, %1, %2" : "=v"(r) : "v"(lo), "v"(hi));
    return r;
}
__device__ __forceinline__ float fast_tanh(float x) {
    const float ax = fabsf(x);
    const float e = __expf(2.f * ax);            // inf for large ax -> r = 1
    const float r = 1.f - 2.f / (e + 1.f);
    return copysignf(r, x);
}

// ---------------------------------------------------------------------------
// Pre-pass: 2 weight matrices [512][100] f32 -> bf16 MFMA B-fragments.
// (Only w_Vi_0 and w_Vt_1 needed: broadcast conditioning branches are
//  constant along the softmax axis and cancel exactly.)
// frag(t, gk): lane l holds W[k = gk*32 + (l>>4)*8 + j][col = t*16 + (l&15)].
// ---------------------------------------------------------------------------
__global__ void preswz_kernel(const float* __restrict__ w0, const float* __restrict__ w1,
                              unsigned short* __restrict__ ws)
{
    const int l  = threadIdx.x;          // 64
    const int gk = blockIdx.x & 15;
    const int t  = blockIdx.x >> 4;      // 0..6
    const int m  = blockIdx.y;           // 0..1
    const float* W = m ? w1 : w0;
    const int col = t * 16 + (l & 15);
    const int k0  = gk * 32 + (l >> 4) * 8;
    unsigned short* o = ws + (size_t)m * FRAGS + ((size_t)(t * 16 + gk) * 64 + l) * 8;
#pragma unroll
    for (int j = 0; j < 8; ++j) {
        float v = (col < NK) ? W[(size_t)(k0 + j) * NK + col] : 0.f;
        o[j] = f32_bf16(v);
    }
}

// ---------------------------------------------------------------------------
// Main kernel: one block per batch, 512 threads (8 waves), target 4 blocks/CU.
// ---------------------------------------------------------------------------
struct SM {
    short buf[NS * 256];     // 25600 B: bf16 feature K-chunk [50 rows][256 cols]
    float scores[64];        // row partials n-half 0 (incl. bias)
    float part2[64];         // row partials n-half 1
    float P[64];
};

// Chunked score pass: A[64x512](global f32, staged 256-col chunks) x W[512x112].
// Wave (m = wid&3) owns rows 16m..16m+15; n-half (wid>>2) owns tiles t0..t0+tcnt-1.
__device__ __forceinline__ void score_chunked(
    const float* __restrict__ feat, const unsigned short* __restrict__ wsR,
    const float* __restrict__ wPiRow, const float* __restrict__ bvec,
    int nrows, int nclamp, short* __restrict__ buf,
    float* __restrict__ outA, float* __restrict__ outB, int tid)
{
    const int lane = tid & 63, wid = tid >> 6;
    const int m = wid & 3, nh = wid >> 2;
    const int t0 = nh * 4, tcnt = nh ? 3 : 4;
    const int colg = lane & 15, g = lane >> 4;
    const int arow0 = m * 16 + colg;
    const int arow = (arow0 < nclamp) ? arow0 : nclamp;   // clamp padded rows
    const int rswz = arow & 7;

    const unsigned short* wbase[4];
#pragma unroll
    for (int q = 0; q < 4; ++q)
        wbase[q] = wsR + (size_t)(t0 + q) * (KSTEPS * 512) + lane * 8;

    const f32x4 zero4 = {0.f, 0.f, 0.f, 0.f};
    f32x4 acc[4] = {zero4, zero4, zero4, zero4};

    const int nitems = nrows * 32;

    for (int chunk = 0; chunk < 2; ++chunk) {
        __syncthreads();   // buf free (prior phase / prior chunk GEMM done)
        // ---- stage chunk: global f32 -> bf16 LDS, 16B-chunk XOR swizzle
        for (int it = tid; it < nitems; it += 512) {
            const int r = it >> 5, c = it & 31;
            const float* p = feat + (r << 9) + (chunk << 8) + (c << 3);
            const float4 a  = *reinterpret_cast<const float4*>(p);
            const float4 b4 = *reinterpret_cast<const float4*>(p + 4);
            uint4 v;
            v.x = cvt_pk_bf16(a.x, a.y);   v.y = cvt_pk_bf16(a.z, a.w);
            v.z = cvt_pk_bf16(b4.x, b4.y); v.w = cvt_pk_bf16(b4.z, b4.w);
            *reinterpret_cast<uint4*>(&buf[(r << 8) + ((c ^ (r & 7)) << 3)]) = v;
        }
        __syncthreads();

        // ---- GEMM on this chunk: 8 k-steps, depth-2 weight prefetch
        const int gk0 = chunk * CHUNK_KS;
        short8 wf[2][4];
#pragma unroll
        for (int s = 0; s < 2; ++s)
#pragma unroll
            for (int q = 0; q < 4; ++q)
                if (q < tcnt) wf[s][q] = *reinterpret_cast<const short8*>(wbase[q] + (gk0 + s) * 512);

#pragma unroll
        for (int ks = 0; ks < CHUNK_KS; ++ks) {
            const short8 a = *reinterpret_cast<const short8*>(
                &buf[(arow << 8) + ((((ks << 2) + g) ^ rswz) << 3)]);
            short8 cur[4];
#pragma unroll
            for (int q = 0; q < 4; ++q) cur[q] = wf[ks & 1][q];
            if (ks + 2 < CHUNK_KS) {
#pragma unroll
                for (int q = 0; q < 4; ++q)
                    if (q < tcnt) wf[ks & 1][q] = *reinterpret_cast<const short8*>(wbase[q] + (gk0 + ks + 2) * 512);
            }
#pragma unroll
            for (int q = 0; q < 4; ++q)
                if (q < tcnt) acc[q] = __builtin_amdgcn_mfma_f32_16x16x32_bf16(a, cur[q], acc[q], 0, 0, 0);
        }
    }

    // ---- epilogue: s[row] = sum_cols tanh(D) * wPiRow; shfl-reduce 16 col-lanes
    float s[4] = {0.f, 0.f, 0.f, 0.f};
#pragma unroll
    for (int q = 0; q < 4; ++q)
        if (q < tcnt) {
            const int col = (t0 + q) * 16 + colg;
            const float w = (col < NK) ? wPiRow[col] : 0.f;
#pragma unroll
            for (int i = 0; i < 4; ++i) s[i] += fast_tanh(acc[q][i]) * w;
        }
#pragma unroll
    for (int off = 1; off < 16; off <<= 1) {
#pragma unroll
        for (int i = 0; i < 4; ++i) s[i] += __shfl_xor(s[i], off);
    }
    if (colg == 0) {
        float* o = nh ? outB : outA;
        const int rbase = m * 16 + g * 4;
#pragma unroll
        for (int i = 0; i < 4; ++i) {
            const int r = rbase + i;
            if (r < nrows) o[r] = s[i] + (nh ? 0.f : bvec[r]);
        }
    }
}

__global__ __launch_bounds__(512, 8) void coattn_main(
    const float* __restrict__ ifeat, const float* __restrict__ tfeat,
    const float* __restrict__ wPi0, const float* __restrict__ bPi0,
    const float* __restrict__ wPi1, const float* __restrict__ bPi1,
    const unsigned short* __restrict__ wsW, float* __restrict__ out)
{
    __shared__ SM sm;
    const int b = blockIdx.x, tid = threadIdx.x;
    const float* ig = ifeat + (size_t)b * NR * ND;
    const float* tg = tfeat + (size_t)b * NS * ND;

    // ---- pass 0: scores_i (conditioning branch cancels in softmax)
    score_chunked(ig, wsW, wPi0, bPi0, NR, NR - 1, sm.buf, sm.scores, sm.part2, tid);
    __syncthreads();

    if (tid < 64) {   // softmax over R
        const float v = (tid < NR) ? sm.scores[tid] + sm.part2[tid] : -3.0e38f;
        float mx = v;
#pragma unroll
        for (int off = 32; off; off >>= 1) mx = fmaxf(mx, __shfl_xor(mx, off));
        const float e = (tid < NR) ? __expf(v - mx) : 0.f;
        float su = e;
#pragma unroll
        for (int off = 32; off; off >>= 1) su += __shfl_xor(su, off);
        sm.P[tid] = e / su;
    }
    __syncthreads();

    // ---- vi[tid] = sum_r P[r] * I[r, tid]   (global f32, coalesced, L2/L3-hot)
    float viv = 0.f;
    {
        const float* ip = ig + tid;
#pragma unroll 7
        for (int r = 0; r < NR; ++r) viv += sm.P[r] * ip[r << 9];
    }

    // ---- pass 1: scores_t (conditioning branch cancels in softmax)
    score_chunked(tg, wsW + (size_t)FRAGS, wPi1 + NK, bPi1, NS, NS - 1,
                  sm.buf, sm.scores, sm.part2, tid);
    __syncthreads();

    if (tid < 64) {   // softmax over S
        const float v = (tid < NS) ? sm.scores[tid] + sm.part2[tid] : -3.0e38f;
        float mx = v;
#pragma unroll
        for (int off = 32; off; off >>= 1) mx = fmaxf(mx, __shfl_xor(mx, off));
        const float e = (tid < NS) ? __expf(v - mx) : 0.f;
        float su = e;
#pragma unroll
        for (int off = 32; off; off >>= 1) su += __shfl_xor(su, off);
        sm.P[tid] = e / su;
    }
    __syncthreads();

    // ---- out[tid] = vi + sum_s P[s] * T[s, tid]   (global f32, coalesced)
    {
        float o = viv;
        const float* tp = tg + tid;
#pragma unroll 10
        for (int s = 0; s < NS; ++s) o += sm.P[s] * tp[s << 9];
        out[(size_t)b * ND + tid] = o;
    }
}

extern "C" void kernel_launch(void* const* d_in, const int* in_sizes, int n_in,
                              void* d_out, int out_size, void* d_ws, size_t ws_size,
                              hipStream_t stream) {
    const float* ifeat = (const float*)d_in[0];
    const float* tfeat = (const float*)d_in[1];
    const float* wVi0  = (const float*)d_in[2];
    const float* wPi0  = (const float*)d_in[4];
    const float* bPi0  = (const float*)d_in[5];
    const float* wVt1  = (const float*)d_in[7];
    const float* wPi1  = (const float*)d_in[8];
    const float* bPi1  = (const float*)d_in[9];
    float* outp = (float*)d_out;
    unsigned short* wsW = (unsigned short*)d_ws;   // 2*114688 = 229376 B

    hipLaunchKernelGGL(preswz_kernel, dim3(NT * KSTEPS, 2), dim3(64), 0, stream,
                       wVi0, wVt1, wsW);
    hipLaunchKernelGGL(coattn_main, dim3(NB), dim3(512), 0, stream,
                       ifeat, tfeat, wPi0, bPi0, wPi1, bPi1, wsW, outp);
}

// Round 6
// 315.879 us; speedup vs baseline: 3.2542x; 3.2542x over previous
//
#include <hip/hip_runtime.h>
#include <math.h>

#define NB 4096
#define NR 49
#define NS 50
#define ND 512
#define NK 100
#define NT 7            // N-tiles of 16 cols (112 >= 100)
#define KSTEPS 16       // 512 / 32 (global k-steps)
#define CHUNK_KS 8      // k-steps per LDS chunk (256 cols)
#define FRAGS (NT * KSTEPS * 64 * 8)   // 57344 ushorts (114688 B) per weight matrix

typedef __attribute__((ext_vector_type(8))) short short8;
typedef __attribute__((ext_vector_type(4))) float f32x4;

__device__ __forceinline__ unsigned short f32_bf16(float f) {
    union { float f; unsigned u; } x; x.f = f;
    return (unsigned short)((x.u + 0x7fffu + ((x.u >> 16) & 1u)) >> 16);  // RNE
}
__device__ __forceinline__ unsigned cvt_pk_bf16(float lo, float hi) {
    unsigned r;
    asm("v_cvt_pk_bf16_f32 %0, %1, %2" : "=v"(r) : "v"(lo), "v"(hi));
    return r;
}
__device__ __forceinline__ float fast_tanh(float x) {
    const float ax = fabsf(x);
    const float e = __expf(2.f * ax);            // inf for large ax -> r = 1
    const float r = 1.f - 2.f / (e + 1.f);
    return copysignf(r, x);
}

// ---------------------------------------------------------------------------
// Pre-pass: 2 weight matrices [512][100] f32 -> bf16 MFMA B-fragments.
// (Only w_Vi_0 and w_Vt_1 needed: broadcast conditioning branches are
//  constant along the softmax axis and cancel exactly; consequently the two
//  attention passes are fully independent.)
// frag(t, gk): lane l holds W[k = gk*32 + (l>>4)*8 + j][col = t*16 + (l&15)].
// ---------------------------------------------------------------------------
__global__ void preswz_kernel(const float* __restrict__ w0, const float* __restrict__ w1,
                              unsigned short* __restrict__ ws)
{
    const int l  = threadIdx.x;          // 64
    const int gk = blockIdx.x & 15;
    const int t  = blockIdx.x >> 4;      // 0..6
    const int m  = blockIdx.y;           // 0..1
    const float* W = m ? w1 : w0;
    const int col = t * 16 + (l & 15);
    const int k0  = gk * 32 + (l >> 4) * 8;
    unsigned short* o = ws + (size_t)m * FRAGS + ((size_t)(t * 16 + gk) * 64 + l) * 8;
#pragma unroll
    for (int j = 0; j < 8; ++j) {
        float v = (col < NK) ? W[(size_t)(k0 + j) * NK + col] : 0.f;
        o[j] = f32_bf16(v);
    }
}

// ---------------------------------------------------------------------------
// Main kernel: one block per (batch, pass), 512 threads (8 waves).
// Each block: stage features -> GEMM scores -> softmax -> weighted sum ->
// atomicAdd into out (out pre-zeroed; 2 commutative f32 adds = deterministic).
// ---------------------------------------------------------------------------
struct SM {
    short buf[NS * 256];     // 25600 B: bf16 feature K-chunk [50 rows][256 cols]
    float scores[64];        // row partials n-half 0 (incl. bias)
    float part2[64];         // row partials n-half 1
    float P[64];
};

__global__ __launch_bounds__(512, 4) void coattn_main(
    const float* __restrict__ ifeat, const float* __restrict__ tfeat,
    const float* __restrict__ wPi0, const float* __restrict__ bPi0,
    const float* __restrict__ wPi1, const float* __restrict__ bPi1,
    const unsigned short* __restrict__ wsW, float* __restrict__ out)
{
    __shared__ SM sm;
    const int pass = blockIdx.x & 1;
    const int b    = blockIdx.x >> 1;
    const int tid  = threadIdx.x;

    const float* feat = pass ? (tfeat + (size_t)b * NS * ND) : (ifeat + (size_t)b * NR * ND);
    const int nrows  = pass ? NS : NR;
    const int nclamp = nrows - 1;
    const unsigned short* wsR = wsW + (size_t)pass * FRAGS;
    const float* wPiRow = pass ? (wPi1 + NK) : wPi0;
    const float* bvec   = pass ? bPi1 : bPi0;

    const int lane = tid & 63, wid = tid >> 6;
    const int m = wid & 3, nh = wid >> 2;
    const int t0 = nh * 4, tcnt = nh ? 3 : 4;
    const int colg = lane & 15, g = lane >> 4;
    const int arow0 = m * 16 + colg;
    const int arow = (arow0 < nclamp) ? arow0 : nclamp;   // clamp padded rows
    const int rswz = arow & 7;

    const unsigned short* wbase[4];
#pragma unroll
    for (int q = 0; q < 4; ++q)
        wbase[q] = wsR + (size_t)(t0 + q) * (KSTEPS * 512) + lane * 8;

    const f32x4 zero4 = {0.f, 0.f, 0.f, 0.f};
    f32x4 acc[4] = {zero4, zero4, zero4, zero4};

    const int nitems = nrows * 32;

    for (int chunk = 0; chunk < 2; ++chunk) {
        __syncthreads();   // buf free (prior chunk's GEMM done)
        // ---- stage chunk: global f32 -> bf16 LDS, 16B-chunk XOR swizzle
        for (int it = tid; it < nitems; it += 512) {
            const int r = it >> 5, c = it & 31;
            const float* p = feat + (r << 9) + (chunk << 8) + (c << 3);
            const float4 a  = *reinterpret_cast<const float4*>(p);
            const float4 b4 = *reinterpret_cast<const float4*>(p + 4);
            uint4 v;
            v.x = cvt_pk_bf16(a.x, a.y);   v.y = cvt_pk_bf16(a.z, a.w);
            v.z = cvt_pk_bf16(b4.x, b4.y); v.w = cvt_pk_bf16(b4.z, b4.w);
            *reinterpret_cast<uint4*>(&sm.buf[(r << 8) + ((c ^ (r & 7)) << 3)]) = v;
        }
        __syncthreads();

        // ---- GEMM on this chunk: 8 k-steps, depth-2 weight prefetch
        const int gk0 = chunk * CHUNK_KS;
        short8 wf[2][4];
#pragma unroll
        for (int s = 0; s < 2; ++s)
#pragma unroll
            for (int q = 0; q < 4; ++q)
                if (q < tcnt) wf[s][q] = *reinterpret_cast<const short8*>(wbase[q] + (gk0 + s) * 512);

#pragma unroll
        for (int ks = 0; ks < CHUNK_KS; ++ks) {
            const short8 a = *reinterpret_cast<const short8*>(
                &sm.buf[(arow << 8) + ((((ks << 2) + g) ^ rswz) << 3)]);
            short8 cur[4];
#pragma unroll
            for (int q = 0; q < 4; ++q) cur[q] = wf[ks & 1][q];
            if (ks + 2 < CHUNK_KS) {
#pragma unroll
                for (int q = 0; q < 4; ++q)
                    if (q < tcnt) wf[ks & 1][q] = *reinterpret_cast<const short8*>(wbase[q] + (gk0 + ks + 2) * 512);
            }
#pragma unroll
            for (int q = 0; q < 4; ++q)
                if (q < tcnt) acc[q] = __builtin_amdgcn_mfma_f32_16x16x32_bf16(a, cur[q], acc[q], 0, 0, 0);
        }
    }

    // ---- epilogue: s[row] = sum_cols tanh(D) * wPiRow; shfl-reduce 16 col-lanes
    {
        float s[4] = {0.f, 0.f, 0.f, 0.f};
#pragma unroll
        for (int q = 0; q < 4; ++q)
            if (q < tcnt) {
                const int col = (t0 + q) * 16 + colg;
                const float w = (col < NK) ? wPiRow[col] : 0.f;
#pragma unroll
                for (int i = 0; i < 4; ++i) s[i] += fast_tanh(acc[q][i]) * w;
            }
#pragma unroll
        for (int off = 1; off < 16; off <<= 1) {
#pragma unroll
            for (int i = 0; i < 4; ++i) s[i] += __shfl_xor(s[i], off);
        }
        if (colg == 0) {
            float* o = nh ? sm.part2 : sm.scores;
            const int rbase = m * 16 + g * 4;
#pragma unroll
            for (int i = 0; i < 4; ++i) {
                const int r = rbase + i;
                if (r < nrows) o[r] = s[i] + (nh ? 0.f : bvec[r]);
            }
        }
    }
    __syncthreads();

    if (tid < 64) {   // softmax over rows
        const float v = (tid < nrows) ? sm.scores[tid] + sm.part2[tid] : -3.0e38f;
        float mx = v;
#pragma unroll
        for (int off = 32; off; off >>= 1) mx = fmaxf(mx, __shfl_xor(mx, off));
        const float e = (tid < nrows) ? __expf(v - mx) : 0.f;
        float su = e;
#pragma unroll
        for (int off = 32; off; off >>= 1) su += __shfl_xor(su, off);
        sm.P[tid] = e / su;
    }
    __syncthreads();

    // ---- weighted sum: V[tid] = sum_r P[r] * feat[r, tid]  (global f32, L2/L3-hot)
    {
        float v = 0.f;
        const float* fp = feat + tid;
        for (int r = 0; r < nrows; ++r) v += sm.P[r] * fp[r << 9];
        atomicAdd(&out[(size_t)b * ND + tid], v);
    }
}

extern "C" void kernel_launch(void* const* d_in, const int* in_sizes, int n_in,
                              void* d_out, int out_size, void* d_ws, size_t ws_size,
                              hipStream_t stream) {
    const float* ifeat = (const float*)d_in[0];
    const float* tfeat = (const float*)d_in[1];
    const float* wVi0  = (const float*)d_in[2];
    const float* wPi0  = (const float*)d_in[4];
    const float* bPi0  = (const float*)d_in[5];
    const float* wVt1  = (const float*)d_in[7];
    const float* wPi1  = (const float*)d_in[8];
    const float* bPi1  = (const float*)d_in[9];
    float* outp = (float*)d_out;
    unsigned short* wsW = (unsigned short*)d_ws;   // 2*114688 = 229376 B

    hipMemsetAsync(outp, 0, (size_t)NB * ND * sizeof(float), stream);
    hipLaunchKernelGGL(preswz_kernel, dim3(NT * KSTEPS, 2), dim3(64), 0, stream,
                       wVi0, wVt1, wsW);
    hipLaunchKernelGGL(coattn_main, dim3(2 * NB), dim3(512), 0, stream,
                       ifeat, tfeat, wPi0, bPi0, wPi1, bPi1, wsW, outp);
}